// Round 10
// baseline (249.692 us; speedup 1.0000x reference)
//
#include <hip/hip_runtime.h>
#include <stdint.h>

#define B_ 10000
#define T_ 80
#define E_ 100
#define U_ 64

typedef __attribute__((ext_vector_type(8))) short bf16x8;
typedef __attribute__((ext_vector_type(4))) float f32x4;

union FragU { bf16x8 v; uint32_t u[4]; short s[8]; };
union LdU  { uint4 q4; bf16x8 v; };

__device__ __forceinline__ void split_bf16(float w, short& hi, short& lo) {
    uint32_t wb  = __float_as_uint(w);
    uint32_t hib = wb & 0xFFFF0000u;
    float rem = w - __uint_as_float(hib);   // exact
    hi = (short)(hib >> 16);
    lo = (short)(__float_as_uint(rem) >> 16);
}

__device__ __forceinline__ short bf16_rne(float w) {
    uint32_t u = __float_as_uint(w);
    uint32_t r = (u + 0x7FFFu + ((u >> 16) & 1u)) >> 16;
    return (short)r;
}

__device__ __forceinline__ float tanh_fast(float v) {
    float e  = __expf(2.0f * fabsf(v));     // overflow -> inf -> tanh -> 1
    float r  = __builtin_amdgcn_rcpf(e + 1.0f);
    float tn = fmaf(-2.0f, r, 1.0f);
    uint32_t res = (__float_as_uint(tn) & 0x7FFFFFFFu) | (__float_as_uint(v) & 0x80000000u);
    return __uint_as_float(res);
}

__device__ __forceinline__ float sigmoid_f(float logit) {
    if (logit >= 0.0f) return __builtin_amdgcn_rcpf(1.0f + __expf(-logit));
    float e = __expf(logit);
    return e * __builtin_amdgcn_rcpf(1.0f + e);
}

// gather 28 valid floats of one emb row slice for lane (q,*)
__device__ __forceinline__ void gather_x(const float* __restrict__ erow, int q, f32x4 xf[7]) {
    #pragma unroll
    for (int kk = 0; kk < 3; ++kk) {
        const int k0 = 8 * q + 32 * kk;            // max 88; +7 = 95 < 100
        xf[2 * kk]     = *(const f32x4*)(erow + k0);
        xf[2 * kk + 1] = *(const f32x4*)(erow + k0 + 4);
    }
    xf[6] = *(const f32x4*)(erow + 96);
}

// 28 f32 -> 4 bf16 A-fragments (truncation pack)
__device__ __forceinline__ void cvt_x(const f32x4 xf[7], FragU ax[4]) {
    #pragma unroll
    for (int kk = 0; kk < 3; ++kk) {
        ax[kk].u[0] = __builtin_amdgcn_perm(__float_as_uint(xf[2*kk][1]),   __float_as_uint(xf[2*kk][0]),   0x07060302u);
        ax[kk].u[1] = __builtin_amdgcn_perm(__float_as_uint(xf[2*kk][3]),   __float_as_uint(xf[2*kk][2]),   0x07060302u);
        ax[kk].u[2] = __builtin_amdgcn_perm(__float_as_uint(xf[2*kk+1][1]), __float_as_uint(xf[2*kk+1][0]), 0x07060302u);
        ax[kk].u[3] = __builtin_amdgcn_perm(__float_as_uint(xf[2*kk+1][3]), __float_as_uint(xf[2*kk+1][2]), 0x07060302u);
    }
    ax[3].u[0] = __builtin_amdgcn_perm(__float_as_uint(xf[6][1]), __float_as_uint(xf[6][0]), 0x07060302u);
    ax[3].u[1] = __builtin_amdgcn_perm(__float_as_uint(xf[6][3]), __float_as_uint(xf[6][2]), 0x07060302u);
    ax[3].u[2] = ax[3].u[0];   // k>=100 rows of Wx frag are zero
    ax[3].u[3] = ax[3].u[1];
}

#define MFMA(A, Bf, C) __builtin_amdgcn_mfma_f32_16x16x32_bf16((A), (Bf), (C), 0, 0, 0)

// ============ fused RNN v10: 1 wave = TWO independent 16-row groups (A,B), phase-interleaved.
// Dual dependency chains fill each other's stalls; no barriers; h via bf16 hi/lo LDS + b128 reads. ============
__global__ __launch_bounds__(64, 1)
void rnn_v10(const int* __restrict__ tokens, const float* __restrict__ emb,
             const float* __restrict__ Wx, const float* __restrict__ Wh,
             const float* __restrict__ bias, const float* __restrict__ Wfc,
             const float* __restrict__ bfc, float* __restrict__ out)
{
    __shared__ __align__(16) unsigned short HhiA[16 * 64], HloA[16 * 64];
    __shared__ __align__(16) unsigned short HhiB[16 * 64], HloB[16 * 64];
    __shared__ int toksA[16 * T_], toksB[16 * T_];

    const int l = threadIdx.x;
    const int q = l >> 4, p = l & 15;
    const int R0A = blockIdx.x * 32;
    const int R0B_real = R0A + 16;
    const bool haveB = (R0B_real + 16) <= B_;          // last block: B duplicates A, writes suppressed
    const int R0B = haveB ? R0B_real : R0A;

    for (int i = l; i < 16 * T_; i += 64) {
        toksA[i] = tokens[R0A * T_ + i];
        toksB[i] = tokens[R0B * T_ + i];
    }

    // ---- Wx fragments: 1-term RNE (shared by both groups) ----
    FragU wxh[4][4];
    #pragma unroll
    for (int kk = 0; kk < 4; ++kk)
        #pragma unroll
        for (int n = 0; n < 4; ++n)
            #pragma unroll
            for (int j = 0; j < 8; ++j) {
                int k = 8 * q + j + 32 * kk;
                float v = (k < E_) ? Wx[k * U_ + 16 * n + p] : 0.0f;
                wxh[kk][n].s[j] = bf16_rne(v);
            }
    // ---- Wh fragments: exact hi/lo ----
    FragU whh[2][4], whl[2][4];
    #pragma unroll
    for (int kk = 0; kk < 2; ++kk)
        #pragma unroll
        for (int n = 0; n < 4; ++n)
            #pragma unroll
            for (int j = 0; j < 8; ++j) {
                float v = Wh[(8 * q + j + 32 * kk) * U_ + 16 * n + p];
                split_bf16(v, whh[kk][n].s[j], whl[kk][n].s[j]);
            }

    float bv[4], wf[4];
    #pragma unroll
    for (int n = 0; n < 4; ++n) { bv[n] = bias[16 * n + p]; wf[n] = Wfc[16 * n + p]; }
    const f32x4 z4 = {0.0f, 0.0f, 0.0f, 0.0f};

    // ---- h(0)=0 both groups (single wave: DS in-order) ----
    { uint32_t* a0 = (uint32_t*)HhiA; uint32_t* a1 = (uint32_t*)HloA;
      uint32_t* b0 = (uint32_t*)HhiB; uint32_t* b1 = (uint32_t*)HloB;
      for (int i = l; i < 512; i += 64) { a0[i]=0u; a1[i]=0u; b0[i]=0u; b1[i]=0u; } }

    const int rswz   = (p & 7) << 3;
    const int rdoff0 = p * 64 + ((8 * q)      ^ rswz);
    const int rdoff1 = p * 64 + ((32 + 8 * q) ^ rswz);

    // ---- prologue (both groups): P(0); x(1) in flight ----
    f32x4 XA[7], XB[7];
    f32x4 PA[4], PB[4];
    int tokcA, tokcB;
    {
        FragU ax[4];
        gather_x(emb + (size_t)toksA[p * T_ + 0] * E_, q, XA);
        gather_x(emb + (size_t)toksB[p * T_ + 0] * E_, q, XB);
        cvt_x(XA, ax);
        #pragma unroll
        for (int n = 0; n < 4; ++n) {
            f32x4 bn = {bv[n], bv[n], bv[n], bv[n]};
            f32x4 c = MFMA(ax[0].v, wxh[0][n].v, bn);
            c = MFMA(ax[1].v, wxh[1][n].v, c);
            c = MFMA(ax[2].v, wxh[2][n].v, c);
            c = MFMA(ax[3].v, wxh[3][n].v, c);
            PA[n] = c;
        }
        cvt_x(XB, ax);
        #pragma unroll
        for (int n = 0; n < 4; ++n) {
            f32x4 bn = {bv[n], bv[n], bv[n], bv[n]};
            f32x4 c = MFMA(ax[0].v, wxh[0][n].v, bn);
            c = MFMA(ax[1].v, wxh[1][n].v, c);
            c = MFMA(ax[2].v, wxh[2][n].v, c);
            c = MFMA(ax[3].v, wxh[3][n].v, c);
            PB[n] = c;
        }
        gather_x(emb + (size_t)toksA[p * T_ + 1] * E_, q, XA);
        gather_x(emb + (size_t)toksB[p * T_ + 1] * E_, q, XB);
        tokcA = toksA[p * T_ + 2];
        tokcB = toksB[p * T_ + 2];
    }

    LdU ah0A, ah1A, al0A, al1A, ah0B, ah1B, al0B, al1B;
    ah0A.q4 = *(const uint4*)(HhiA + rdoff0);  ah1A.q4 = *(const uint4*)(HhiA + rdoff1);
    al0A.q4 = *(const uint4*)(HloA + rdoff0);  al1A.q4 = *(const uint4*)(HloA + rdoff1);
    ah0B.q4 = *(const uint4*)(HhiB + rdoff0);  ah1B.q4 = *(const uint4*)(HhiB + rdoff1);
    al0B.q4 = *(const uint4*)(HloB + rdoff0);  al1B.q4 = *(const uint4*)(HloB + rdoff1);

    float hlA[16], hlB[16];

#define PH_CVT(S)                                                                  \
    FragU axn##S[4];                                                               \
    cvt_x(X##S, axn##S);                                                           \
    gather_x(emb + (size_t)tokc##S * E_, q, X##S);                                 \
    { int ti = t + 3; if (ti > T_ - 1) ti = T_ - 1; tokc##S = toks##S[p * T_ + ti]; }

#define PH_REC(S)                                                                  \
    f32x4 acc##S[4];                                                               \
    _Pragma("unroll")                                                              \
    for (int n = 0; n < 4; ++n) {                                                  \
        f32x4 c1 = MFMA(ah0##S.v, whh[0][n].v, P##S[n]);                           \
        c1       = MFMA(ah1##S.v, whh[1][n].v, c1);                                \
        f32x4 c2 = MFMA(al0##S.v, whh[0][n].v, z4);                                \
        c2       = MFMA(al1##S.v, whh[1][n].v, c2);                                \
        c2       = MFMA(ah0##S.v, whl[0][n].v, c2);                                \
        c2       = MFMA(ah1##S.v, whl[1][n].v, c2);                                \
        acc##S[n] = c1 + c2;                                                       \
    }

#define PH_TANH(S)                                                                 \
    _Pragma("unroll")                                                              \
    for (int r = 0; r < 4; ++r) {                                                  \
        const int row   = 4 * q + r;                                               \
        const int wbase = row * 64;                                                \
        const int wswz  = (row & 7) << 3;                                          \
        _Pragma("unroll")                                                          \
        for (int n = 0; n < 4; ++n) {                                              \
            float h = tanh_fast(acc##S[n][r]);                                     \
            hl##S[r * 4 + n] = h;                                                  \
            uint32_t hb  = __float_as_uint(h);                                     \
            uint32_t hib = hb & 0xFFFF0000u;                                       \
            float rem = h - __uint_as_float(hib);                                  \
            const int idx = wbase + ((16 * n + p) ^ wswz);                         \
            Hhi##S[idx] = (unsigned short)(hb >> 16);                              \
            Hlo##S[idx] = (unsigned short)(__float_as_uint(rem) >> 16);            \
        }                                                                          \
    }

#define PH_READ(S)                                                                 \
    ah0##S.q4 = *(const uint4*)(Hhi##S + rdoff0);                                  \
    ah1##S.q4 = *(const uint4*)(Hhi##S + rdoff1);                                  \
    al0##S.q4 = *(const uint4*)(Hlo##S + rdoff0);                                  \
    al1##S.q4 = *(const uint4*)(Hlo##S + rdoff1);

#define PH_PROJ(S)                                                                 \
    _Pragma("unroll")                                                              \
    for (int n = 0; n < 4; ++n) {                                                  \
        f32x4 bn = {bv[n], bv[n], bv[n], bv[n]};                                   \
        f32x4 c = MFMA(axn##S[0].v, wxh[0][n].v, bn);                              \
        c = MFMA(axn##S[1].v, wxh[1][n].v, c);                                     \
        c = MFMA(axn##S[2].v, wxh[2][n].v, c);                                     \
        c = MFMA(axn##S[3].v, wxh[3][n].v, c);                                     \
        P##S[n] = c;                                                               \
    }

    for (int t = 0; t < T_; ++t) {
        PH_CVT(A)  PH_CVT(B)
        PH_REC(A)  PH_REC(B)
        PH_TANH(A) PH_TANH(B)
        PH_READ(A) PH_READ(B)
        PH_PROJ(A) PH_PROJ(B)
    }
#undef PH_CVT
#undef PH_REC
#undef PH_TANH
#undef PH_READ
#undef PH_PROJ

    // ---- logits + sigmoid ----
    #pragma unroll
    for (int r = 0; r < 4; ++r) {
        float pa = hlA[r * 4 + 0] * wf[0] + hlA[r * 4 + 1] * wf[1]
                 + hlA[r * 4 + 2] * wf[2] + hlA[r * 4 + 3] * wf[3];
        pa += __shfl_xor(pa, 1);
        pa += __shfl_xor(pa, 2);
        pa += __shfl_xor(pa, 4);
        pa += __shfl_xor(pa, 8);
        float pb = hlB[r * 4 + 0] * wf[0] + hlB[r * 4 + 1] * wf[1]
                 + hlB[r * 4 + 2] * wf[2] + hlB[r * 4 + 3] * wf[3];
        pb += __shfl_xor(pb, 1);
        pb += __shfl_xor(pb, 2);
        pb += __shfl_xor(pb, 4);
        pb += __shfl_xor(pb, 8);
        if (p == 0) {
            out[R0A + 4 * q + r] = sigmoid_f(pa + bfc[0]);
            if (haveB) out[R0B_real + 4 * q + r] = sigmoid_f(pb + bfc[0]);
        }
    }
}

extern "C" void kernel_launch(void* const* d_in, const int* in_sizes, int n_in,
                              void* d_out, int out_size, void* d_ws, size_t ws_size,
                              hipStream_t stream) {
    const int*   tokens = (const int*)  d_in[0];
    const float* emb    = (const float*)d_in[1];
    const float* Wx     = (const float*)d_in[2];
    const float* Wh     = (const float*)d_in[3];
    const float* b      = (const float*)d_in[4];
    const float* Wfc    = (const float*)d_in[5];
    const float* bfc    = (const float*)d_in[6];
    float* out          = (float*)d_out;

    const int grid = (B_ + 31) / 32;   // 313: last block single-group
    rnn_v10<<<grid, 64, 0, stream>>>(tokens, emb, Wx, Wh, b, Wfc, bfc, out);
}

// Round 11
// 128.236 us; speedup vs baseline: 1.9471x; 1.9471x over previous
//
#include <hip/hip_runtime.h>
#include <stdint.h>

#define B_ 10000
#define T_ 80
#define E_ 100
#define U_ 64

typedef __attribute__((ext_vector_type(8))) short bf16x8;
typedef __attribute__((ext_vector_type(4))) float f32x4;

union FragU { bf16x8 v; uint32_t u[4]; short s[8]; };
union LdU  { uint4 q4; bf16x8 v; };

__device__ __forceinline__ void split_bf16(float w, short& hi, short& lo) {
    uint32_t wb  = __float_as_uint(w);
    uint32_t hib = wb & 0xFFFF0000u;
    float rem = w - __uint_as_float(hib);   // exact
    hi = (short)(hib >> 16);
    lo = (short)(__float_as_uint(rem) >> 16);
}

__device__ __forceinline__ unsigned short bf16_rne(float w) {
    uint32_t u = __float_as_uint(w);
    uint32_t r = (u + 0x7FFFu + ((u >> 16) & 1u)) >> 16;
    return (unsigned short)r;
}

// valid for both signs: v->+inf gives 1, v->-inf gives -1, never NaN for finite v
__device__ __forceinline__ float tanh_fast5(float v) {
    float e = __expf(2.0f * v);
    float r = __builtin_amdgcn_rcpf(e + 1.0f);
    return fmaf(-2.0f, r, 1.0f);
}

__device__ __forceinline__ float sigmoid_f(float logit) {
    if (logit >= 0.0f) return __builtin_amdgcn_rcpf(1.0f + __expf(-logit));
    float e = __expf(logit);
    return e * __builtin_amdgcn_rcpf(1.0f + e);
}

// gather 28 valid floats of one emb row slice for lane (q,*)
__device__ __forceinline__ void gather_x(const float* __restrict__ erow, int q, f32x4 xf[7]) {
    #pragma unroll
    for (int kk = 0; kk < 3; ++kk) {
        const int k0 = 8 * q + 32 * kk;            // max 88; +7 = 95 < 100
        xf[2 * kk]     = *(const f32x4*)(erow + k0);
        xf[2 * kk + 1] = *(const f32x4*)(erow + k0 + 4);
    }
    xf[6] = *(const f32x4*)(erow + 96);
}

// 28 f32 -> 4 bf16 A-fragments (truncation pack)
__device__ __forceinline__ void cvt_x(const f32x4 xf[7], FragU ax[4]) {
    #pragma unroll
    for (int kk = 0; kk < 3; ++kk) {
        ax[kk].u[0] = __builtin_amdgcn_perm(__float_as_uint(xf[2*kk][1]),   __float_as_uint(xf[2*kk][0]),   0x07060302u);
        ax[kk].u[1] = __builtin_amdgcn_perm(__float_as_uint(xf[2*kk][3]),   __float_as_uint(xf[2*kk][2]),   0x07060302u);
        ax[kk].u[2] = __builtin_amdgcn_perm(__float_as_uint(xf[2*kk+1][1]), __float_as_uint(xf[2*kk+1][0]), 0x07060302u);
        ax[kk].u[3] = __builtin_amdgcn_perm(__float_as_uint(xf[2*kk+1][3]), __float_as_uint(xf[2*kk+1][2]), 0x07060302u);
    }
    ax[3].u[0] = __builtin_amdgcn_perm(__float_as_uint(xf[6][1]), __float_as_uint(xf[6][0]), 0x07060302u);
    ax[3].u[1] = __builtin_amdgcn_perm(__float_as_uint(xf[6][3]), __float_as_uint(xf[6][2]), 0x07060302u);
    ax[3].u[2] = ax[3].u[0];   // k>=100 rows of Wx frag are zero
    ax[3].u[3] = ax[3].u[1];
}

#define MFMA(A, Bf, C) __builtin_amdgcn_mfma_f32_16x16x32_bf16((A), (Bf), (C), 0, 0, 0)

// ============ fused RNN v11: 1 wave = 16 rows, no barriers; 2-term rec (h RNE-bf16, Wh exact hi/lo);
// proj off critical path; single-chain MFMA per n; minimal VALU ============
__global__ __launch_bounds__(64, 1)
void rnn_v11(const int* __restrict__ tokens, const float* __restrict__ emb,
             const float* __restrict__ Wx, const float* __restrict__ Wh,
             const float* __restrict__ bias, const float* __restrict__ Wfc,
             const float* __restrict__ bfc, float* __restrict__ out)
{
    // h as single RNE bf16: [row 16][unit 64], 8-col-granular XOR swizzle
    __shared__ __align__(16) unsigned short Hq[16 * 64];
    __shared__ int toks[16 * T_];

    const int l = threadIdx.x;
    const int q = l >> 4, p = l & 15;
    const int R0 = blockIdx.x * 16;

    for (int i = l; i < 16 * T_; i += 64) toks[i] = tokens[R0 * T_ + i];

    // ---- Wx fragments: 1-term RNE ----
    FragU wxh[4][4];
    #pragma unroll
    for (int kk = 0; kk < 4; ++kk)
        #pragma unroll
        for (int n = 0; n < 4; ++n)
            #pragma unroll
            for (int j = 0; j < 8; ++j) {
                int k = 8 * q + j + 32 * kk;
                float v = (k < E_) ? Wx[k * U_ + 16 * n + p] : 0.0f;
                wxh[kk][n].s[j] = (short)bf16_rne(v);
            }
    // ---- Wh fragments: exact hi/lo (2-term recurrence: h_q @ (Whh + Whl)) ----
    FragU whh[2][4], whl[2][4];
    #pragma unroll
    for (int kk = 0; kk < 2; ++kk)
        #pragma unroll
        for (int n = 0; n < 4; ++n)
            #pragma unroll
            for (int j = 0; j < 8; ++j) {
                float v = Wh[(8 * q + j + 32 * kk) * U_ + 16 * n + p];
                split_bf16(v, whh[kk][n].s[j], whl[kk][n].s[j]);
            }

    float bv[4], wf[4];
    #pragma unroll
    for (int n = 0; n < 4; ++n) { bv[n] = bias[16 * n + p]; wf[n] = Wfc[16 * n + p]; }

    // read offsets (u16 index): row p, col (8q | 32+8q) ^ ((p&7)<<3)  -- 16B aligned
    const int rswz   = (p & 7) << 3;
    const int rdoff0 = p * 64 + ((8 * q)      ^ rswz);
    const int rdoff1 = p * 64 + ((32 + 8 * q) ^ rswz);

    // ---- prologue: P(0) from x(0); x(1) in flight ----
    f32x4 X[7];
    f32x4 P[4];
    {
        FragU ax[4];
        gather_x(emb + (size_t)toks[p * T_ + 0] * E_, q, X);
        cvt_x(X, ax);
        #pragma unroll
        for (int n = 0; n < 4; ++n) {
            f32x4 bn = {bv[n], bv[n], bv[n], bv[n]};
            f32x4 c = MFMA(ax[0].v, wxh[0][n].v, bn);
            c = MFMA(ax[1].v, wxh[1][n].v, c);
            c = MFMA(ax[2].v, wxh[2][n].v, c);
            c = MFMA(ax[3].v, wxh[3][n].v, c);
            P[n] = c;
        }
        gather_x(emb + (size_t)toks[p * T_ + 1] * E_, q, X);
    }
    int tokc = toks[p * T_ + 2];

    // h(0) = 0 directly in fragment registers — no LDS init, no pre-read
    LdU ah0, ah1;
    ah0.q4 = (uint4){0, 0, 0, 0};
    ah1.q4 = (uint4){0, 0, 0, 0};

    f32x4 acc[4];

    for (int t = 0; t < T_; ++t) {
        // x(t+1) fragments (gather landed during previous step); reissue x(t+2)
        FragU axn[4];
        cvt_x(X, axn);
        gather_x(emb + (size_t)tokc * E_, q, X);
        int ti = t + 3; if (ti > T_ - 1) ti = T_ - 1;
        const int tokn = toks[p * T_ + ti];

        // ---- recurrence: single depth-4 chain per n, seeded with P(t) ----
        #pragma unroll
        for (int n = 0; n < 4; ++n) {
            f32x4 c = MFMA(ah0.v, whh[0][n].v, P[n]);
            c = MFMA(ah1.v, whh[1][n].v, c);
            c = MFMA(ah0.v, whl[0][n].v, c);
            c = MFMA(ah1.v, whl[1][n].v, c);
            acc[n] = c;
        }

        // ---- tanh (5-op) + RNE-bf16 + swizzled b16 write of h(t) ----
        #pragma unroll
        for (int r = 0; r < 4; ++r) {
            const int row   = 4 * q + r;
            const int wbase = row * 64;
            const int wswz  = (row & 7) << 3;
            #pragma unroll
            for (int n = 0; n < 4; ++n) {
                float h = tanh_fast5(acc[n][r]);
                Hq[wbase + ((16 * n + p) ^ wswz)] = bf16_rne(h);
            }
        }

        // ---- read h(t) fragments for next step (latency hidden by proj below) ----
        ah0.q4 = *(const uint4*)(Hq + rdoff0);
        ah1.q4 = *(const uint4*)(Hq + rdoff1);

        // ---- proj for t+1 (off critical path) ----
        #pragma unroll
        for (int n = 0; n < 4; ++n) {
            f32x4 bn = {bv[n], bv[n], bv[n], bv[n]};
            f32x4 c = MFMA(axn[0].v, wxh[0][n].v, bn);
            c = MFMA(axn[1].v, wxh[1][n].v, c);
            c = MFMA(axn[2].v, wxh[2][n].v, c);
            c = MFMA(axn[3].v, wxh[3][n].v, c);
            P[n] = c;
        }
        tokc = tokn;
    }

    // ---- logits + sigmoid (recompute h from final acc) ----
    #pragma unroll
    for (int r = 0; r < 4; ++r) {
        float part = tanh_fast5(acc[0][r]) * wf[0] + tanh_fast5(acc[1][r]) * wf[1]
                   + tanh_fast5(acc[2][r]) * wf[2] + tanh_fast5(acc[3][r]) * wf[3];
        part += __shfl_xor(part, 1);
        part += __shfl_xor(part, 2);
        part += __shfl_xor(part, 4);
        part += __shfl_xor(part, 8);
        if (p == 0) out[R0 + 4 * q + r] = sigmoid_f(part + bfc[0]);
    }
}

extern "C" void kernel_launch(void* const* d_in, const int* in_sizes, int n_in,
                              void* d_out, int out_size, void* d_ws, size_t ws_size,
                              hipStream_t stream) {
    const int*   tokens = (const int*)  d_in[0];
    const float* emb    = (const float*)d_in[1];
    const float* Wx     = (const float*)d_in[2];
    const float* Wh     = (const float*)d_in[3];
    const float* b      = (const float*)d_in[4];
    const float* Wfc    = (const float*)d_in[5];
    const float* bfc    = (const float*)d_in[6];
    float* out          = (float*)d_out;

    rnn_v11<<<B_ / 16, 64, 0, stream>>>(tokens, emb, Wx, Wh, b, Wfc, bfc, out);
}

// Round 12
// 125.052 us; speedup vs baseline: 1.9967x; 1.0255x over previous
//
#include <hip/hip_runtime.h>
#include <stdint.h>

#define B_ 10000
#define T_ 80
#define E_ 100
#define U_ 64

typedef __attribute__((ext_vector_type(8))) short bf16x8;
typedef __attribute__((ext_vector_type(4))) float f32x4;

union FragU { bf16x8 v; uint32_t u[4]; short s[8]; };
union LdU  { uint4 q4; bf16x8 v; };

__device__ __forceinline__ unsigned short bf16_rne(float w) {
    uint32_t u = __float_as_uint(w);
    uint32_t r = (u + 0x7FFFu + ((u >> 16) & 1u)) >> 16;
    return (unsigned short)r;
}

// tanh(v) = 1 - 2/(exp2(v*2*log2e)+1); valid both signs, +-inf -> +-1, no NaN
__device__ __forceinline__ float tanh_fast(float v) {
    float e = __builtin_amdgcn_exp2f(v * 2.8853900817779268f);
    float r = __builtin_amdgcn_rcpf(e + 1.0f);
    return fmaf(-2.0f, r, 1.0f);
}

__device__ __forceinline__ float sigmoid_f(float logit) {
    if (logit >= 0.0f) return __builtin_amdgcn_rcpf(1.0f + __expf(-logit));
    float e = __expf(logit);
    return e * __builtin_amdgcn_rcpf(1.0f + e);
}

// gather 28 valid floats of one emb row slice for lane (q,*)
__device__ __forceinline__ void gather_x(const float* __restrict__ erow, int q, f32x4 xf[7]) {
    #pragma unroll
    for (int kk = 0; kk < 3; ++kk) {
        const int k0 = 8 * q + 32 * kk;            // max 88; +7 = 95 < 100
        xf[2 * kk]     = *(const f32x4*)(erow + k0);
        xf[2 * kk + 1] = *(const f32x4*)(erow + k0 + 4);
    }
    xf[6] = *(const f32x4*)(erow + 96);
}

// 28 f32 -> 4 bf16 A-fragments (truncation pack)
__device__ __forceinline__ void cvt_x(const f32x4 xf[7], FragU ax[4]) {
    #pragma unroll
    for (int kk = 0; kk < 3; ++kk) {
        ax[kk].u[0] = __builtin_amdgcn_perm(__float_as_uint(xf[2*kk][1]),   __float_as_uint(xf[2*kk][0]),   0x07060302u);
        ax[kk].u[1] = __builtin_amdgcn_perm(__float_as_uint(xf[2*kk][3]),   __float_as_uint(xf[2*kk][2]),   0x07060302u);
        ax[kk].u[2] = __builtin_amdgcn_perm(__float_as_uint(xf[2*kk+1][1]), __float_as_uint(xf[2*kk+1][0]), 0x07060302u);
        ax[kk].u[3] = __builtin_amdgcn_perm(__float_as_uint(xf[2*kk+1][3]), __float_as_uint(xf[2*kk+1][2]), 0x07060302u);
    }
    ax[3].u[0] = __builtin_amdgcn_perm(__float_as_uint(xf[6][1]), __float_as_uint(xf[6][0]), 0x07060302u);
    ax[3].u[1] = __builtin_amdgcn_perm(__float_as_uint(xf[6][3]), __float_as_uint(xf[6][2]), 0x07060302u);
    ax[3].u[2] = ax[3].u[0];   // k>=100 rows of Wx frag are zero
    ax[3].u[3] = ax[3].u[1];
}

#define MFMA(A, Bf, C) __builtin_amdgcn_mfma_f32_16x16x32_bf16((A), (Bf), (C), 0, 0, 0)

// ============ fused RNN v12: 1 wave = 16 rows, no barriers; 1-term RNE Wh (rec depth-2, 8 MFMA);
// proj off critical path; minimal VALU; unroll-1 loop ============
__global__ __launch_bounds__(64, 1)
void rnn_v12(const int* __restrict__ tokens, const float* __restrict__ emb,
             const float* __restrict__ Wx, const float* __restrict__ Wh,
             const float* __restrict__ bias, const float* __restrict__ Wfc,
             const float* __restrict__ bfc, float* __restrict__ out)
{
    // h as single RNE bf16: [row 16][unit 64], 8-col-granular XOR swizzle
    __shared__ __align__(16) unsigned short Hq[16 * 64];
    __shared__ int toks[16 * T_];

    const int l = threadIdx.x;
    const int q = l >> 4, p = l & 15;
    const int R0 = blockIdx.x * 16;

    for (int i = l; i < 16 * T_; i += 64) toks[i] = tokens[R0 * T_ + i];

    // ---- Wx fragments: 1-term RNE ----
    FragU wxh[4][4];
    #pragma unroll
    for (int kk = 0; kk < 4; ++kk)
        #pragma unroll
        for (int n = 0; n < 4; ++n)
            #pragma unroll
            for (int j = 0; j < 8; ++j) {
                int k = 8 * q + j + 32 * kk;
                float v = (k < E_) ? Wx[k * U_ + 16 * n + p] : 0.0f;
                wxh[kk][n].s[j] = (short)bf16_rne(v);
            }
    // ---- Wh fragments: 1-term RNE ----
    FragU wh[2][4];
    #pragma unroll
    for (int kk = 0; kk < 2; ++kk)
        #pragma unroll
        for (int n = 0; n < 4; ++n)
            #pragma unroll
            for (int j = 0; j < 8; ++j) {
                float v = Wh[(8 * q + j + 32 * kk) * U_ + 16 * n + p];
                wh[kk][n].s[j] = (short)bf16_rne(v);
            }

    float bv[4], wf[4];
    #pragma unroll
    for (int n = 0; n < 4; ++n) { bv[n] = bias[16 * n + p]; wf[n] = Wfc[16 * n + p]; }

    // read offsets (u16 index): row p, col (8q | 32+8q) ^ ((p&7)<<3)  -- 16B aligned
    const int rswz   = (p & 7) << 3;
    const int rdoff0 = p * 64 + ((8 * q)      ^ rswz);
    const int rdoff1 = p * 64 + ((32 + 8 * q) ^ rswz);

    // ---- prologue: P(0) from x(0); x(1) in flight ----
    f32x4 X[7];
    f32x4 P[4];
    {
        FragU ax[4];
        gather_x(emb + (size_t)toks[p * T_ + 0] * E_, q, X);
        cvt_x(X, ax);
        #pragma unroll
        for (int n = 0; n < 4; ++n) {
            f32x4 bn = {bv[n], bv[n], bv[n], bv[n]};
            f32x4 c = MFMA(ax[0].v, wxh[0][n].v, bn);
            c = MFMA(ax[1].v, wxh[1][n].v, c);
            c = MFMA(ax[2].v, wxh[2][n].v, c);
            c = MFMA(ax[3].v, wxh[3][n].v, c);
            P[n] = c;
        }
        gather_x(emb + (size_t)toks[p * T_ + 1] * E_, q, X);
    }
    int tokc = toks[p * T_ + 2];

    // h(0) = 0 directly in fragment registers — no LDS init, no pre-read
    LdU ah0, ah1;
    ah0.q4 = (uint4){0, 0, 0, 0};
    ah1.q4 = (uint4){0, 0, 0, 0};

    f32x4 acc[4];

    #pragma unroll 1
    for (int t = 0; t < T_; ++t) {
        // x(t+1) fragments (gather landed during previous step); reissue x(t+2)
        FragU axn[4];
        cvt_x(X, axn);
        gather_x(emb + (size_t)tokc * E_, q, X);
        int ti = t + 3; if (ti > T_ - 1) ti = T_ - 1;
        const int tokn = toks[p * T_ + ti];

        // ---- recurrence: depth-2 chain per n, seeded with P(t) ----
        #pragma unroll
        for (int n = 0; n < 4; ++n) {
            f32x4 c = MFMA(ah0.v, wh[0][n].v, P[n]);
            c = MFMA(ah1.v, wh[1][n].v, c);
            acc[n] = c;
        }

        // ---- tanh + RNE-bf16 + swizzled b16 write of h(t) ----
        #pragma unroll
        for (int r = 0; r < 4; ++r) {
            const int row   = 4 * q + r;
            const int wbase = row * 64;
            const int wswz  = (row & 7) << 3;
            #pragma unroll
            for (int n = 0; n < 4; ++n) {
                float h = tanh_fast(acc[n][r]);
                Hq[wbase + ((16 * n + p) ^ wswz)] = bf16_rne(h);
            }
        }

        // ---- read h(t) fragments for next step (latency hidden by proj below) ----
        ah0.q4 = *(const uint4*)(Hq + rdoff0);
        ah1.q4 = *(const uint4*)(Hq + rdoff1);

        // ---- proj for t+1 (off critical path) ----
        #pragma unroll
        for (int n = 0; n < 4; ++n) {
            f32x4 bn = {bv[n], bv[n], bv[n], bv[n]};
            f32x4 c = MFMA(axn[0].v, wxh[0][n].v, bn);
            c = MFMA(axn[1].v, wxh[1][n].v, c);
            c = MFMA(axn[2].v, wxh[2][n].v, c);
            c = MFMA(axn[3].v, wxh[3][n].v, c);
            P[n] = c;
        }
        tokc = tokn;
    }

    // ---- logits + sigmoid (recompute h from final acc) ----
    #pragma unroll
    for (int r = 0; r < 4; ++r) {
        float part = tanh_fast(acc[0][r]) * wf[0] + tanh_fast(acc[1][r]) * wf[1]
                   + tanh_fast(acc[2][r]) * wf[2] + tanh_fast(acc[3][r]) * wf[3];
        part += __shfl_xor(part, 1);
        part += __shfl_xor(part, 2);
        part += __shfl_xor(part, 4);
        part += __shfl_xor(part, 8);
        if (p == 0) out[R0 + 4 * q + r] = sigmoid_f(part + bfc[0]);
    }
}

extern "C" void kernel_launch(void* const* d_in, const int* in_sizes, int n_in,
                              void* d_out, int out_size, void* d_ws, size_t ws_size,
                              hipStream_t stream) {
    const int*   tokens = (const int*)  d_in[0];
    const float* emb    = (const float*)d_in[1];
    const float* Wx     = (const float*)d_in[2];
    const float* Wh     = (const float*)d_in[3];
    const float* b      = (const float*)d_in[4];
    const float* Wfc    = (const float*)d_in[5];
    const float* bfc    = (const float*)d_in[6];
    float* out          = (float*)d_out;

    rnn_v12<<<B_ / 16, 64, 0, stream>>>(tokens, emb, Wx, Wh, b, Wfc, bfc, out);
}